// Round 6
// baseline (248.171 us; speedup 1.0000x reference)
//
#include <hip/hip_runtime.h>
#include <hip/hip_bf16.h>
#include <hip/hip_fp16.h>
#include <math.h>

#ifndef M_PI
#define M_PI 3.14159265358979323846
#endif

// Problem constants
#define NN 10000      // nodes
#define NE 160000     // edges
#define NC 16         // channels
#define NQ 5          // 2*order+1
#define NFR 10        // N_FREQ * N_RINGS
#define CQ 80         // NC*NQ
#define OP 80         // outputs per node

// Extended GEMM: k in [0,800) edge-aggregate part with k = cq*10 + fr;
//                k in [800,880) self-interaction part with k = 800 + cq;
//                k in [880,896) zero pad (both A and B written as 0).
#define KTOT2 896
#define KS 28         // 896 / 32 MFMA k-steps
#define WTN 71680     // KTOT2 * 80 weight elements per layer
#define APAD 936      // LDS row stride fp16: 468 dwords = 20 mod 32 banks (v12-proven residue)

typedef __attribute__((ext_vector_type(8))) _Float16 f16x8;
typedef __attribute__((ext_vector_type(4))) float f32x4;

static __device__ __forceinline__ unsigned short f2h_u(float f) {
    return __builtin_bit_cast(unsigned short, (_Float16)f);
}
static __device__ __forceinline__ unsigned pack2h(float lo, float hi) {
    return (unsigned)f2h_u(lo) | ((unsigned)f2h_u(hi) << 16);
}

// ---------------------------------------------------------------------------
// prep_all: (a) CSR degree histogram over edges; (b) threads i < WTN reorder
// W+Ws into MFMA-B fragment order (k-map in header comment).
// ---------------------------------------------------------------------------
__global__ void prep_all(const int* __restrict__ ei,
                         const float* __restrict__ W1, const float* __restrict__ Ws1,
                         const float* __restrict__ W2, const float* __restrict__ Ws2,
                         int* __restrict__ cnt,
                         unsigned short* __restrict__ Wt1, unsigned short* __restrict__ Wt2) {
    int i = blockIdx.x * blockDim.x + threadIdx.x;
    if (i < NE) atomicAdd(&cnt[ei[2 * i + 1]], 1);
    if (i < WTN) {
        int j    = i & 7;
        int lane = (i >> 3) & 63;
        int grp  = i >> 9;            // 0..139 = ks*5 + nt
        int ks   = grp / 5;
        int nt   = grp % 5;
        int quad = lane >> 4;
        int lrow = lane & 15;
        int n    = 16 * nt + lrow;    // output index op
        int k    = 32 * ks + 8 * quad + j;
        int o = n / 5, p = n % 5;
        float v1, v2;
        if (k < 800) {                // edge part: k = cq*10 + fr
            int cq = k / 10, fr = k % 10;
            int c = cq / 5, q = cq % 5;
            int f = fr >> 1, r = fr & 1;
            int src = ((((o * NC + c) * NQ + p) * NQ + q) * 5 + f) * 2 + r;
            v1 = W1[src]; v2 = W2[src];
        } else if (k < 880) {         // self part: k = 800 + cq
            int cq = k - 800;
            int c = cq / 5, q = cq % 5;
            int src = ((o * NC + c) * NQ + p) * NQ + q;
            v1 = Ws1[src]; v2 = Ws2[src];
        } else {                      // pad
            v1 = 0.0f; v2 = 0.0f;
        }
        Wt1[i] = f2h_u(v1); Wt2[i] = f2h_u(v2);
    }
}

// ---------------------------------------------------------------------------
// CSR scan: 1 block, 1024 threads, 10 counts each (1000 active) + LDS scan.
// ---------------------------------------------------------------------------
__global__ void csr_scan(const int* __restrict__ cnt, int* __restrict__ offs,
                         int* __restrict__ cursor) {
    __shared__ int part[1024];
    const int t = threadIdx.x;
    const int b0 = t * 10;
    int s = 0;
    if (t < 1000)
        for (int i = 0; i < 10; ++i) s += cnt[b0 + i];
    part[t] = s;
    __syncthreads();
    for (int d = 1; d < 1024; d <<= 1) {
        int u = (t >= d) ? part[t - d] : 0;
        __syncthreads();
        part[t] += u;
        __syncthreads();
    }
    if (t < 1000) {
        int run = (t == 0) ? 0 : part[t - 1];
        for (int i = 0; i < 10; ++i) {
            offs[b0 + i] = run;
            cursor[b0 + i] = run;
            run += cnt[b0 + i];
        }
    }
    if (t == 1023) offs[NN] = part[1023];    // = NE
}

// ---------------------------------------------------------------------------
// csr_place_gather: each edge claims its CSR slot AND writes the aggregation
// working set there in STREAM layout:
//   srcs[pos] = ei[2e];  recs[pos] = {tv[0..9], c1, s1}  (48 B, 3 x float4)
// ---------------------------------------------------------------------------
__global__ void csr_place_gather(const int* __restrict__ ei, const float* __restrict__ phi,
                                 const float* __restrict__ pre,
                                 int* __restrict__ cursor,
                                 int* __restrict__ srcs, float4* __restrict__ recs) {
    int e = blockIdx.x * blockDim.x + threadIdx.x;
    if (e >= NE) return;
    const int dst = ei[2 * e + 1];
    const int srcn = ei[2 * e];
    const int pos = atomicAdd(&cursor[dst], 1);
    float s1, c1;
    sincosf(phi[e], &s1, &c1);
    const float* tp = pre + (size_t)e * NFR;
    float4* rp = recs + (size_t)pos * 3;
    rp[0] = make_float4(tp[0], tp[1], tp[2], tp[3]);
    rp[1] = make_float4(tp[4], tp[5], tp[6], tp[7]);
    rp[2] = make_float4(tp[8], tp[9], c1, s1);
    srcs[pos] = srcn;
}

// ---------------------------------------------------------------------------
// layer_fused (v16): ONE kernel per layer = aggregate -> LDS A-tile -> MFMA
// GEMM (edge conv + self-interaction via extended K) -> bias/residual ->
// 7-sample Fourier nonlinearity -> layer output.
//
// Rationale (R5 post-mortem): v15's separate aggregate showed VGPR=32/LDS=0
// yet OccupancyPercent 38% -> drain/tail dominated (Poisson-16 degrees, one
// team per node). Here each thread aggregates 4 nodes serially (sigma/mu of
// per-thread work halves) and the Agg global buffer (17.9 MB write + 17.9 MB
// read per layer) disappears entirely; B preload hides under aggregation.
//
// Numerics: identical edge math, accumulation order, and single fp16
// quantization as the passing v15 — only the A-row destination changed
// (LDS instead of global).
// ---------------------------------------------------------------------------
__global__ __launch_bounds__(320)
void layer_fused(const float* __restrict__ xin, const int* __restrict__ srcs,
                 const float4* __restrict__ recs, const int* __restrict__ offs,
                 const unsigned short* __restrict__ Wt, const float* __restrict__ b,
                 const float* __restrict__ res,   // residual (x) or nullptr
                 float* __restrict__ outp) {
    __shared__ __align__(16) unsigned short A_s[16 * APAD];  // 29,952 B
    __shared__ float y_s[16 * OP];                           //  5,120 B

    const int tid = threadIdx.x;
    const int n0 = blockIdx.x * 16;              // NN = 625*16 exactly

    // ---- GEMM lane mapping + B preload (latency hides under aggregation) ----
    const int nt = tid >> 6, lane = tid & 63;
    const int lrow = lane & 15, quad = lane >> 4;
    const f16x8* __restrict__ wf = (const f16x8*)Wt;
    f16x8 breg[KS];
    #pragma unroll
    for (int ks = 0; ks < KS; ++ks)
        breg[ks] = wf[(ks * 5 + nt) * 64 + lane];

    // ---- aggregation: team tm (80 threads) handles nodes 4*tm .. 4*tm+3 ----
    const int tm = tid / 80;
    const int cq = tid - tm * 80;
    const int q  = cq % 5;
    const int qp   = (q == 0) ? 0 : ((q & 1) ? q + 1 : q - 1);
    const int pofs = cq - q + qp;                // transport partner column
    const bool is0 = (q == 0);
    const bool hi  = (q >= 3);                   // order-2 pair
    const float sgn = (q == 1 || q == 3) ? -1.0f : 1.0f;

#define EDGE_FMA(r0, r1, r2, xa, xb)                                          \
    do {                                                                      \
        const float c1 = (r2).z, s1 = (r2).w;                                 \
        const float c2 = c1 * c1 - s1 * s1;                                   \
        const float s2 = 2.0f * c1 * s1;                                      \
        const float Ac = is0 ? 1.0f : (hi ? c2 : c1);                         \
        const float Bc = is0 ? 0.0f : sgn * (hi ? s2 : s1);                   \
        const float xt = Ac * (xa) + Bc * (xb);                               \
        acc[0] += xt * (r0).x;  acc[1] += xt * (r0).y;                        \
        acc[2] += xt * (r0).z;  acc[3] += xt * (r0).w;                        \
        acc[4] += xt * (r1).x;  acc[5] += xt * (r1).y;                        \
        acc[6] += xt * (r1).z;  acc[7] += xt * (r1).w;                        \
        acc[8] += xt * (r2).x;  acc[9] += xt * (r2).y;                        \
    } while (0)

    #pragma unroll 1
    for (int i = 0; i < 4; ++i) {
        const int nl = tm * 4 + i;               // local node 0..15
        const int n  = n0 + nl;
        const int beg = offs[n], end = offs[n + 1];

        float acc[10];
        #pragma unroll
        for (int f = 0; f < 10; ++f) acc[f] = 0.0f;

        if (beg < end) {
            // 1-stage srcs pipeline + unroll x2 (v14-proven loop shape)
            int c0 = srcs[beg];
            int c1v = (beg + 1 < end) ? srcs[beg + 1] : c0;
            int idx = beg;
            for (; idx + 2 <= end; idx += 2) {
                const float* xr0 = xin + (size_t)c0 * CQ;
                const float* xr1 = xin + (size_t)c1v * CQ;
                const float xa0 = xr0[cq], xb0 = xr0[pofs];
                const float xa1 = xr1[cq], xb1 = xr1[pofs];
                const float4* rp = recs + (size_t)idx * 3;
                const float4 r00 = rp[0], r01 = rp[1], r02 = rp[2];
                const float4 r10 = rp[3], r11 = rp[4], r12 = rp[5];
                const int t0 = idx + 2, t1 = idx + 3;
                c0  = srcs[t0 < end ? t0 : end - 1];
                c1v = srcs[t1 < end ? t1 : end - 1];
                EDGE_FMA(r00, r01, r02, xa0, xb0);
                EDGE_FMA(r10, r11, r12, xa1, xb1);
            }
            if (idx < end) {                     // tail: c0 == srcs[idx]
                const float* xr = xin + (size_t)c0 * CQ;
                const float xa = xr[cq], xb = xr[pofs];
                const float4* rp = recs + (size_t)idx * 3;
                const float4 r0 = rp[0], r1 = rp[1], r2 = rp[2];
                EDGE_FMA(r0, r1, r2, xa, xb);
            }
        }

        // A-row write: k = cq*10 + fr (same pack order as v15's Agg write)
        unsigned* aw = (unsigned*)&A_s[nl * APAD + cq * 10];
        aw[0] = pack2h(acc[0], acc[1]);
        aw[1] = pack2h(acc[2], acc[3]);
        aw[2] = pack2h(acc[4], acc[5]);
        aw[3] = pack2h(acc[6], acc[7]);
        aw[4] = pack2h(acc[8], acc[9]);
        // self-interaction column + zero pad
        A_s[nl * APAD + 800 + cq] = f2h_u(xin[(size_t)n * CQ + cq]);
        if (cq < 16) A_s[nl * APAD + 880 + cq] = 0;
    }
#undef EDGE_FMA

    __syncthreads();

    // ---- GEMM: y[16 x 80] = A_s[16 x 896] @ B'[896 x 80] ----
    f32x4 acc = (f32x4){0.f, 0.f, 0.f, 0.f};
    #pragma unroll
    for (int ks = 0; ks < KS; ++ks) {
        f16x8 a = *(const f16x8*)(&A_s[lrow * APAD + 32 * ks + 8 * quad]);
        acc = __builtin_amdgcn_mfma_f32_16x16x32_f16(a, breg[ks], acc, 0, 0, 0);
    }

    const int op = 16 * nt + lrow;
    const float bias = (op % 5 == 0) ? b[op / 5] : 0.0f;
    #pragma unroll
    for (int r = 0; r < 4; ++r)
        y_s[(quad * 4 + r) * OP + op] = acc[r] + bias;
    __syncthreads();

    // ---- epilogue: 256 threads, one (node, channel) each ----
    if (tid < 256) {
        const int nl = tid >> 4;                 // node 0..15
        const int c  = tid & 15;                 // channel
        const float* vp = &y_s[nl * OP + c * 5];
        float a0 = vp[0], a1 = vp[1], a2 = vp[2], a3 = vp[3], a4 = vp[4];
        if (res != nullptr) {
            const float* rp = res + (size_t)(n0 + nl) * CQ + c * 5;
            a0 += rp[0]; a1 += rp[1]; a2 += rp[2]; a3 += rp[3]; a4 += rp[4];
        }
        float o0 = 0.f, o1 = 0.f, o2 = 0.f, o3 = 0.f, o4 = 0.f;
        #pragma unroll
        for (int k = 0; k < 7; ++k) {
            float th = (float)(2.0 * M_PI / 7.0) * (float)k;
            float c1k = cosf(th), s1k = sinf(th);
            float c2k = cosf(2.0f * th), s2k = sinf(2.0f * th);
            float s = a0 + a1 * c1k + a2 * s1k + a3 * c2k + a4 * s2k;
            s = fmaxf(s, 0.0f);
            o0 += s;
            o1 += s * c1k; o2 += s * s1k;
            o3 += s * c2k; o4 += s * s2k;
        }
        const float i7 = 1.0f / 7.0f, t7 = 2.0f / 7.0f;
        float* po = outp + (size_t)(n0 + nl) * OP + c * 5;
        po[0] = o0 * i7;
        po[1] = o1 * t7; po[2] = o2 * t7;
        po[3] = o3 * t7; po[4] = o4 * t7;
    }
}

// ---------------------------------------------------------------------------
extern "C" void kernel_launch(void* const* d_in, const int* in_sizes, int n_in,
                              void* d_out, int out_size, void* d_ws, size_t ws_size,
                              hipStream_t stream) {
    const float* x    = (const float*)d_in[0];
    const int*   ei   = (const int*)d_in[1];      // int inputs arrive as int32
    const float* pre  = (const float*)d_in[2];
    const float* phi  = (const float*)d_in[3];
    const float* W1   = (const float*)d_in[4];
    const float* b1   = (const float*)d_in[5];
    const float* Ws1  = (const float*)d_in[6];
    const float* W2   = (const float*)d_in[7];
    const float* b2   = (const float*)d_in[8];
    const float* Ws2  = (const float*)d_in[9];
    float* out = (float*)d_out;

    // Workspace layout (~12.5 MB)
    unsigned short* Wt1 = (unsigned short*)d_ws;            // 143.4 KB
    unsigned short* Wt2 = Wt1 + WTN;                        // 143.4 KB
    float* h  = (float*)(Wt2 + WTN);                        // 3.2 MB
    float4* recs = (float4*)(h + (size_t)NN * OP);          // 7.68 MB (16B aligned)
    int* srcs   = (int*)(recs + (size_t)NE * 3);            // 640 KB
    int* cnt    = srcs + NE;                                // 40 KB
    int* offs   = cnt + NN;                                 // 40 KB
    int* cursor = offs + NN + 1;                            // 40 KB

    // prep: hist + W/Ws reorder; scan; place+gather (stream-ordered records)
    hipMemsetAsync(cnt, 0, NN * sizeof(int), stream);
    prep_all<<<(NE + 255) / 256, 256, 0, stream>>>(ei, W1, Ws1, W2, Ws2, cnt, Wt1, Wt2);
    csr_scan<<<1, 1024, 0, stream>>>(cnt, offs, cursor);
    csr_place_gather<<<(NE + 255) / 256, 256, 0, stream>>>(ei, phi, pre, cursor, srcs, recs);

    // Layer 1 and Layer 2: one fused kernel each
    layer_fused<<<NN / 16, 320, 0, stream>>>(x, srcs, recs, offs, Wt1, b1, nullptr, h);
    layer_fused<<<NN / 16, 320, 0, stream>>>(h, srcs, recs, offs, Wt2, b2, x, out);
}

// Round 8
// 156.796 us; speedup vs baseline: 1.5828x; 1.5828x over previous
//
#include <hip/hip_runtime.h>
#include <hip/hip_bf16.h>
#include <hip/hip_fp16.h>
#include <math.h>

#ifndef M_PI
#define M_PI 3.14159265358979323846
#endif

// Problem constants
#define NN 10000      // nodes
#define NE 160000     // edges
#define NC 16         // channels
#define NQ 5          // 2*order+1
#define NFR 10        // N_FREQ * N_RINGS
#define CQ 80         // NC*NQ
#define OP 80         // outputs per node

// Extended GEMM: k in [0,800) edge-aggregate part with k = cq*10 + fr;
//                k in [800,880) self-interaction part with k = 800 + cq;
//                k in [880,896) zero pad (both A and B written as 0).
#define KTOT2 896
#define KS 28         // 896 / 32 MFMA k-steps
#define WTN 71680     // KTOT2 * 80 weight elements per layer
#define APAD 936      // LDS row stride fp16: 468 dwords = 20 mod 32 banks (v12-proven residue)

typedef __attribute__((ext_vector_type(8))) _Float16 f16x8;
typedef __attribute__((ext_vector_type(4))) float f32x4;

static __device__ __forceinline__ unsigned short f2h_u(float f) {
    return __builtin_bit_cast(unsigned short, (_Float16)f);
}
static __device__ __forceinline__ unsigned pack2h(float lo, float hi) {
    return (unsigned)f2h_u(lo) | ((unsigned)f2h_u(hi) << 16);
}
#define RFL(x) __builtin_amdgcn_readfirstlane(x)

// ---------------------------------------------------------------------------
// prep_all: (a) CSR degree histogram over edges; (b) threads i < WTN reorder
// W+Ws into MFMA-B fragment order (k-map in header comment).
// ---------------------------------------------------------------------------
__global__ void prep_all(const int* __restrict__ ei,
                         const float* __restrict__ W1, const float* __restrict__ Ws1,
                         const float* __restrict__ W2, const float* __restrict__ Ws2,
                         int* __restrict__ cnt,
                         unsigned short* __restrict__ Wt1, unsigned short* __restrict__ Wt2) {
    int i = blockIdx.x * blockDim.x + threadIdx.x;
    if (i < NE) atomicAdd(&cnt[ei[2 * i + 1]], 1);
    if (i < WTN) {
        int j    = i & 7;
        int lane = (i >> 3) & 63;
        int grp  = i >> 9;            // 0..139 = ks*5 + nt
        int ks   = grp / 5;
        int nt   = grp % 5;
        int quad = lane >> 4;
        int lrow = lane & 15;
        int n    = 16 * nt + lrow;    // output index op
        int k    = 32 * ks + 8 * quad + j;
        int o = n / 5, p = n % 5;
        float v1, v2;
        if (k < 800) {                // edge part: k = cq*10 + fr
            int cq = k / 10, fr = k % 10;
            int c = cq / 5, q = cq % 5;
            int f = fr >> 1, r = fr & 1;
            int src = ((((o * NC + c) * NQ + p) * NQ + q) * 5 + f) * 2 + r;
            v1 = W1[src]; v2 = W2[src];
        } else if (k < 880) {         // self part: k = 800 + cq
            int cq = k - 800;
            int c = cq / 5, q = cq % 5;
            int src = ((o * NC + c) * NQ + p) * NQ + q;
            v1 = Ws1[src]; v2 = Ws2[src];
        } else {                      // pad
            v1 = 0.0f; v2 = 0.0f;
        }
        Wt1[i] = f2h_u(v1); Wt2[i] = f2h_u(v2);
    }
}

// ---------------------------------------------------------------------------
// CSR scan: 1 block, 1024 threads, 10 counts each (1000 active) + LDS scan.
// ---------------------------------------------------------------------------
__global__ void csr_scan(const int* __restrict__ cnt, int* __restrict__ offs,
                         int* __restrict__ cursor) {
    __shared__ int part[1024];
    const int t = threadIdx.x;
    const int b0 = t * 10;
    int s = 0;
    if (t < 1000)
        for (int i = 0; i < 10; ++i) s += cnt[b0 + i];
    part[t] = s;
    __syncthreads();
    for (int d = 1; d < 1024; d <<= 1) {
        int u = (t >= d) ? part[t - d] : 0;
        __syncthreads();
        part[t] += u;
        __syncthreads();
    }
    if (t < 1000) {
        int run = (t == 0) ? 0 : part[t - 1];
        for (int i = 0; i < 10; ++i) {
            offs[b0 + i] = run;
            cursor[b0 + i] = run;
            run += cnt[b0 + i];
        }
    }
    if (t == 1023) offs[NN] = part[1023];    // = NE
}

// ---------------------------------------------------------------------------
// csr_place_gather: each edge claims its CSR slot AND writes the aggregation
// working set there in STREAM layout:
//   srcs[pos] = ei[2e];  recs[pos] = {tv[0..9], c1, s1}  (48 B, 3 x float4)
// ---------------------------------------------------------------------------
__global__ void csr_place_gather(const int* __restrict__ ei, const float* __restrict__ phi,
                                 const float* __restrict__ pre,
                                 int* __restrict__ cursor,
                                 int* __restrict__ srcs, float4* __restrict__ recs) {
    int e = blockIdx.x * blockDim.x + threadIdx.x;
    if (e >= NE) return;
    const int dst = ei[2 * e + 1];
    const int srcn = ei[2 * e];
    const int pos = atomicAdd(&cursor[dst], 1);
    float s1, c1;
    sincosf(phi[e], &s1, &c1);
    const float* tp = pre + (size_t)e * NFR;
    float4* rp = recs + (size_t)pos * 3;
    rp[0] = make_float4(tp[0], tp[1], tp[2], tp[3]);
    rp[1] = make_float4(tp[4], tp[5], tp[6], tp[7]);
    rp[2] = make_float4(tp[8], tp[9], c1, s1);
    srcs[pos] = srcn;
}

// ---------------------------------------------------------------------------
// layer_fused v17: ONE WAVE PER NODE.
//
// R6 post-mortem: v16 fused but cut agg parallelism 4x (thread = 4 nodes
// serial; 3125 waves total) -> occupancy 10%, latency exposed, 73 us.
// v17: 16 waves/block, wave w aggregates node n0+w alone. Per-edge records
// (srcs, recs) are WAVE-UNIFORM -> scalar s_loads into SGPRs (frees the
// per-CU TA pipe; the only vector traffic is the 2-dword x-row gather).
// Lane map (48 active lanes): lane l -> channel c=l/3, group g=l%3:
//   g=0: cq=5c (q0, no partner); g=1: cq=5c+1,5c+2; g=2: cq=5c+3,5c+4.
// Transport partners are IN-LANE (no shuffles, no LDS in the loop).
// accA/accB[10] fp32 in regs; CSR edge order; unroll x2 with 1-deep srcs
// prefetch -> identical accumulation order and values as passing v16.
// GEMM + nonlin phases identical to v16, except B loaded inline (unroll 4)
// to keep VGPR <= 128 so the 16-wave block launches.
// ---------------------------------------------------------------------------
__global__ __launch_bounds__(1024)
void layer_fused(const float* __restrict__ xin, const int* __restrict__ srcs,
                 const float4* __restrict__ recs, const int* __restrict__ offs,
                 const unsigned short* __restrict__ Wt, const float* __restrict__ b,
                 const float* __restrict__ res,   // residual (x) or nullptr
                 float* __restrict__ outp) {
    __shared__ __align__(16) unsigned short A_s[16 * APAD];  // 29,952 B
    __shared__ float y_s[16 * OP];                           //  5,120 B

    const int tid = threadIdx.x;
    const int n0 = blockIdx.x * 16;              // NN = 625*16 exactly
    const int wid = RFL(tid >> 6);               // wave id = local node (SGPR)
    const int lane = tid & 63;
    const int n = n0 + wid;

    // ---- lane roles (clamped for lanes 48..63 -> in-bounds dummy work) ----
    const int l48 = (lane < 48) ? lane : 0;
    const int c   = l48 / 3;
    const int g   = l48 - 3 * c;                 // 0,1,2
    const int cqA = 5 * c + ((g == 0) ? 0 : (g == 1) ? 1 : 3);
    const int cqB = cqA + 1;                     // partner (ignored for g==0)
    const bool hi = (g == 2);

    const int beg = RFL(offs[n]);
    const int end = RFL(offs[n + 1]);

    float accA[10], accB[10];
    #pragma unroll
    for (int f = 0; f < 10; ++f) { accA[f] = 0.f; accB[f] = 0.f; }

    // EDGE: t0..t9,c1,s1 are SGPR (uniform); xa/xb per-lane VGPR loads.
#define EDGE_FMA(rp, xa, xb)                                                  \
    do {                                                                      \
        const float c1 = (rp)[10], s1 = (rp)[11];                             \
        const float c2 = c1 * c1 - s1 * s1;                                   \
        const float s2 = 2.0f * c1 * s1;                                      \
        const float cs = hi ? c2 : c1;                                        \
        const float sn = hi ? s2 : s1;                                        \
        const float xtA = (g == 0) ? (xa) : (cs * (xa) - sn * (xb));          \
        const float xtB = sn * (xa) + cs * (xb);                              \
        accA[0] += xtA * (rp)[0];  accB[0] += xtB * (rp)[0];                  \
        accA[1] += xtA * (rp)[1];  accB[1] += xtB * (rp)[1];                  \
        accA[2] += xtA * (rp)[2];  accB[2] += xtB * (rp)[2];                  \
        accA[3] += xtA * (rp)[3];  accB[3] += xtB * (rp)[3];                  \
        accA[4] += xtA * (rp)[4];  accB[4] += xtB * (rp)[4];                  \
        accA[5] += xtA * (rp)[5];  accB[5] += xtB * (rp)[5];                  \
        accA[6] += xtA * (rp)[6];  accB[6] += xtB * (rp)[6];                  \
        accA[7] += xtA * (rp)[7];  accB[7] += xtB * (rp)[7];                  \
        accA[8] += xtA * (rp)[8];  accB[8] += xtB * (rp)[8];                  \
        accA[9] += xtA * (rp)[9];  accB[9] += xtB * (rp)[9];                  \
    } while (0)

    if (beg < end) {
        int s0 = RFL(srcs[beg]);
        int s1i = (beg + 1 < end) ? RFL(srcs[beg + 1]) : s0;
        int idx = beg;
        for (; idx + 2 <= end; idx += 2) {
            const float* xr0 = xin + (size_t)s0 * CQ;
            const float* xr1 = xin + (size_t)s1i * CQ;
            const float xa0 = xr0[cqA], xb0 = xr0[cqB];
            const float xa1 = xr1[cqA], xb1 = xr1[cqB];
            const float* rp0 = (const float*)(recs + (size_t)idx * 3);
            const float* rp1 = rp0 + 12;
            const int t0 = idx + 2, t1 = idx + 3;
            s0  = RFL(srcs[t0 < end ? t0 : end - 1]);
            s1i = RFL(srcs[t1 < end ? t1 : end - 1]);
            EDGE_FMA(rp0, xa0, xb0);
            EDGE_FMA(rp1, xa1, xb1);
        }
        if (idx < end) {                         // tail: s0 == srcs[idx]
            const float* xr = xin + (size_t)s0 * CQ;
            const float xa = xr[cqA], xb = xr[cqB];
            const float* rp = (const float*)(recs + (size_t)idx * 3);
            EDGE_FMA(rp, xa, xb);
        }
    }
#undef EDGE_FMA

    // ---- A-row write (k = cq*10 + fr), self column, zero pad ----
    if (lane < 48) {
        unsigned* awA = (unsigned*)&A_s[wid * APAD + cqA * 10];
        awA[0] = pack2h(accA[0], accA[1]);
        awA[1] = pack2h(accA[2], accA[3]);
        awA[2] = pack2h(accA[4], accA[5]);
        awA[3] = pack2h(accA[6], accA[7]);
        awA[4] = pack2h(accA[8], accA[9]);
        A_s[wid * APAD + 800 + cqA] = f2h_u(xin[(size_t)n * CQ + cqA]);
        if (g != 0) {
            unsigned* awB = (unsigned*)&A_s[wid * APAD + cqB * 10];
            awB[0] = pack2h(accB[0], accB[1]);
            awB[1] = pack2h(accB[2], accB[3]);
            awB[2] = pack2h(accB[4], accB[5]);
            awB[3] = pack2h(accB[6], accB[7]);
            awB[4] = pack2h(accB[8], accB[9]);
            A_s[wid * APAD + 800 + cqB] = f2h_u(xin[(size_t)n * CQ + cqB]);
        }
    }
    if (lane < 16) A_s[wid * APAD + 880 + lane] = 0;

    __syncthreads();

    // ---- GEMM: y[16 x 80] = A_s[16 x 896] @ B'[896 x 80] (waves 0-4) ----
    if (tid < 320) {
        const int nt = tid >> 6, lq = tid & 63;
        const int lrow = lq & 15, quad = lq >> 4;
        const f16x8* __restrict__ wf = (const f16x8*)Wt;
        f32x4 acc = (f32x4){0.f, 0.f, 0.f, 0.f};
        #pragma unroll 4
        for (int ks = 0; ks < KS; ++ks) {
            f16x8 bfrag = wf[(ks * 5 + nt) * 64 + lq];
            f16x8 a = *(const f16x8*)(&A_s[lrow * APAD + 32 * ks + 8 * quad]);
            acc = __builtin_amdgcn_mfma_f32_16x16x32_f16(a, bfrag, acc, 0, 0, 0);
        }
        const int op = 16 * nt + lrow;
        const float bias = (op % 5 == 0) ? b[op / 5] : 0.0f;
        #pragma unroll
        for (int r = 0; r < 4; ++r)
            y_s[(quad * 4 + r) * OP + op] = acc[r] + bias;
    }
    __syncthreads();

    // ---- epilogue: 256 threads, one (node, channel) each ----
    if (tid < 256) {
        const int nl = tid >> 4;                 // node 0..15
        const int ch = tid & 15;                 // channel
        const float* vp = &y_s[nl * OP + ch * 5];
        float a0 = vp[0], a1 = vp[1], a2 = vp[2], a3 = vp[3], a4 = vp[4];
        if (res != nullptr) {
            const float* rp = res + (size_t)(n0 + nl) * CQ + ch * 5;
            a0 += rp[0]; a1 += rp[1]; a2 += rp[2]; a3 += rp[3]; a4 += rp[4];
        }
        float o0 = 0.f, o1 = 0.f, o2 = 0.f, o3 = 0.f, o4 = 0.f;
        #pragma unroll
        for (int k = 0; k < 7; ++k) {
            float th = (float)(2.0 * M_PI / 7.0) * (float)k;
            float c1k = cosf(th), s1k = sinf(th);
            float c2k = cosf(2.0f * th), s2k = sinf(2.0f * th);
            float s = a0 + a1 * c1k + a2 * s1k + a3 * c2k + a4 * s2k;
            s = fmaxf(s, 0.0f);
            o0 += s;
            o1 += s * c1k; o2 += s * s1k;
            o3 += s * c2k; o4 += s * s2k;
        }
        const float i7 = 1.0f / 7.0f, t7 = 2.0f / 7.0f;
        float* po = outp + (size_t)(n0 + nl) * OP + ch * 5;
        po[0] = o0 * i7;
        po[1] = o1 * t7; po[2] = o2 * t7;
        po[3] = o3 * t7; po[4] = o4 * t7;
    }
}

// ---------------------------------------------------------------------------
extern "C" void kernel_launch(void* const* d_in, const int* in_sizes, int n_in,
                              void* d_out, int out_size, void* d_ws, size_t ws_size,
                              hipStream_t stream) {
    const float* x    = (const float*)d_in[0];
    const int*   ei   = (const int*)d_in[1];      // int inputs arrive as int32
    const float* pre  = (const float*)d_in[2];
    const float* phi  = (const float*)d_in[3];
    const float* W1   = (const float*)d_in[4];
    const float* b1   = (const float*)d_in[5];
    const float* Ws1  = (const float*)d_in[6];
    const float* W2   = (const float*)d_in[7];
    const float* b2   = (const float*)d_in[8];
    const float* Ws2  = (const float*)d_in[9];
    float* out = (float*)d_out;

    // Workspace layout (~12.5 MB)
    unsigned short* Wt1 = (unsigned short*)d_ws;            // 143.4 KB
    unsigned short* Wt2 = Wt1 + WTN;                        // 143.4 KB
    float* h  = (float*)(Wt2 + WTN);                        // 3.2 MB
    float4* recs = (float4*)(h + (size_t)NN * OP);          // 7.68 MB (16B aligned)
    int* srcs   = (int*)(recs + (size_t)NE * 3);            // 640 KB
    int* cnt    = srcs + NE;                                // 40 KB
    int* offs   = cnt + NN;                                 // 40 KB
    int* cursor = offs + NN + 1;                            // 40 KB

    // prep: hist + W/Ws reorder; scan; place+gather (stream-ordered records)
    hipMemsetAsync(cnt, 0, NN * sizeof(int), stream);
    prep_all<<<(NE + 255) / 256, 256, 0, stream>>>(ei, W1, Ws1, W2, Ws2, cnt, Wt1, Wt2);
    csr_scan<<<1, 1024, 0, stream>>>(cnt, offs, cursor);
    csr_place_gather<<<(NE + 255) / 256, 256, 0, stream>>>(ei, phi, pre, cursor, srcs, recs);

    // Layer 1 and Layer 2: one fused kernel each, one wave per node
    layer_fused<<<NN / 16, 1024, 0, stream>>>(x, srcs, recs, offs, Wt1, b1, nullptr, h);
    layer_fused<<<NN / 16, 1024, 0, stream>>>(h, srcs, recs, offs, Wt2, b2, x, out);
}

// Round 9
// 150.380 us; speedup vs baseline: 1.6503x; 1.0427x over previous
//
#include <hip/hip_runtime.h>
#include <hip/hip_bf16.h>
#include <hip/hip_fp16.h>
#include <math.h>

#ifndef M_PI
#define M_PI 3.14159265358979323846
#endif

// Problem constants
#define NN 10000      // nodes
#define NE 160000     // edges
#define NC 16         // channels
#define NQ 5          // 2*order+1
#define NFR 10        // N_FREQ * N_RINGS
#define CQ 80         // NC*NQ
#define OP 80         // outputs per node

// Fixed-bucket edge store: node n owns slots [n*MAXDEG, n*MAXDEG+deg).
// deg ~ Binomial(160000,1e-4): mean 16, sd 4; 64 = 12 sd -> safe for any seed.
#define MAXDEG 64

// Extended GEMM: k in [0,800) edge-aggregate part with k = cq*10 + fr;
//                k in [800,880) self-interaction part with k = 800 + cq;
//                k in [880,896) zero pad (both A and B written as 0).
#define KTOT2 896
#define KS 28         // 896 / 32 MFMA k-steps
#define WTN 71680     // KTOT2 * 80 weight elements per layer
#define APAD 936      // LDS row stride fp16: 468 dwords = 20 mod 32 banks (v12-proven residue)

typedef __attribute__((ext_vector_type(8))) _Float16 f16x8;
typedef __attribute__((ext_vector_type(4))) float f32x4;

static __device__ __forceinline__ unsigned short f2h_u(float f) {
    return __builtin_bit_cast(unsigned short, (_Float16)f);
}
static __device__ __forceinline__ unsigned pack2h(float lo, float hi) {
    return (unsigned)f2h_u(lo) | ((unsigned)f2h_u(hi) << 16);
}
#define RFL(x) __builtin_amdgcn_readfirstlane(x)

// ---------------------------------------------------------------------------
// prep_all (v18): ONE dispatch does everything the layers need.
//  i < NE:  edge i claims rank = atomicAdd(cnt[dst]) and writes its record
//           {tv[0..9], c1, s1} (48 B) + src id into node dst's fixed bucket.
//           (No scan, no second pass: bucket base is n*MAXDEG by construction.)
//  i < WTN: reorder W+Ws into MFMA-B fragment order (k-map above, R10-proven).
// ---------------------------------------------------------------------------
__global__ void prep_all(const int* __restrict__ ei, const float* __restrict__ phi,
                         const float* __restrict__ pre,
                         const float* __restrict__ W1, const float* __restrict__ Ws1,
                         const float* __restrict__ W2, const float* __restrict__ Ws2,
                         int* __restrict__ cnt, int* __restrict__ srcs,
                         float4* __restrict__ recs,
                         unsigned short* __restrict__ Wt1, unsigned short* __restrict__ Wt2) {
    int i = blockIdx.x * blockDim.x + threadIdx.x;
    if (i < NE) {
        const int dst  = ei[2 * i + 1];
        const int srcn = ei[2 * i];
        const int rank = atomicAdd(&cnt[dst], 1);
        if (rank < MAXDEG) {               // can't overflow for this dataset; guard vs OOB
            float s1, c1;
            sincosf(phi[i], &s1, &c1);
            const float* tp = pre + (size_t)i * NFR;
            const int slot = dst * MAXDEG + rank;
            float4* rp = recs + (size_t)slot * 3;
            rp[0] = make_float4(tp[0], tp[1], tp[2], tp[3]);
            rp[1] = make_float4(tp[4], tp[5], tp[6], tp[7]);
            rp[2] = make_float4(tp[8], tp[9], c1, s1);
            srcs[slot] = srcn;
        }
    }
    if (i < WTN) {
        int j    = i & 7;
        int lane = (i >> 3) & 63;
        int grp  = i >> 9;            // 0..139 = ks*5 + nt
        int ks   = grp / 5;
        int nt   = grp % 5;
        int quad = lane >> 4;
        int lrow = lane & 15;
        int n    = 16 * nt + lrow;    // output index op
        int k    = 32 * ks + 8 * quad + j;
        int o = n / 5, p = n % 5;
        float v1, v2;
        if (k < 800) {                // edge part: k = cq*10 + fr
            int cq = k / 10, fr = k % 10;
            int c = cq / 5, q = cq % 5;
            int f = fr >> 1, r = fr & 1;
            int src = ((((o * NC + c) * NQ + p) * NQ + q) * 5 + f) * 2 + r;
            v1 = W1[src]; v2 = W2[src];
        } else if (k < 880) {         // self part: k = 800 + cq
            int cq = k - 800;
            int c = cq / 5, q = cq % 5;
            int src = ((o * NC + c) * NQ + p) * NQ + q;
            v1 = Ws1[src]; v2 = Ws2[src];
        } else {                      // pad
            v1 = 0.0f; v2 = 0.0f;
        }
        Wt1[i] = f2h_u(v1); Wt2[i] = f2h_u(v2);
    }
}

// ---------------------------------------------------------------------------
// layer_fused v18: ONE WAVE PER NODE (v17 structure) + fixed buckets +
// full 1-window software pipeline (srcs AND recs prefetched into registers,
// so the only in-loop dependent load is the x gather, whose address is ready
// at window start).
//
// Lane map (48 active lanes): lane l -> channel c=l/3, group g=l%3:
//   g=0: cq=5c (q0, no partner); g=1: cq=5c+1,5c+2; g=2: cq=5c+3,5c+4.
// Transport partners are IN-LANE; per-edge records are wave-uniform (SGPR).
// GEMM (waves 0-4, W-fragment loads inline) and nonlin epilogue unchanged
// from the passing v17.
// ---------------------------------------------------------------------------
__global__ __launch_bounds__(1024)
void layer_fused(const float* __restrict__ xin, const int* __restrict__ srcs,
                 const float4* __restrict__ recs, const int* __restrict__ cnt,
                 const unsigned short* __restrict__ Wt, const float* __restrict__ b,
                 const float* __restrict__ res,   // residual (x) or nullptr
                 float* __restrict__ outp) {
    __shared__ __align__(16) unsigned short A_s[16 * APAD];  // 29,952 B
    __shared__ float y_s[16 * OP];                           //  5,120 B

    const int tid = threadIdx.x;
    const int n0 = blockIdx.x * 16;              // NN = 625*16 exactly
    const int wid = RFL(tid >> 6);               // wave id = local node (SGPR)
    const int lane = tid & 63;
    const int n = n0 + wid;

    // ---- lane roles (clamped for lanes 48..63 -> in-bounds dummy work) ----
    const int l48 = (lane < 48) ? lane : 0;
    const int c   = l48 / 3;
    const int g   = l48 - 3 * c;                 // 0,1,2
    const int cqA = 5 * c + ((g == 0) ? 0 : (g == 1) ? 1 : 3);
    const int cqB = cqA + 1;                     // partner (ignored for g==0)
    const bool hi = (g == 2);

    const int base = n * MAXDEG;
    int deg = RFL(cnt[n]);
    if (deg > MAXDEG) deg = MAXDEG;

    float accA[10], accB[10];
    #pragma unroll
    for (int f = 0; f < 10; ++f) { accA[f] = 0.f; accB[f] = 0.f; }

    // EDGE: record floats are SGPR (uniform); xa/xb per-lane VGPR loads.
#define EDGE_FMA(r0, r1, r2, xa, xb)                                          \
    do {                                                                      \
        const float c1 = (r2).z, s1 = (r2).w;                                 \
        const float c2 = c1 * c1 - s1 * s1;                                   \
        const float s2 = 2.0f * c1 * s1;                                      \
        const float cs = hi ? c2 : c1;                                        \
        const float sn = hi ? s2 : s1;                                        \
        const float xtA = (g == 0) ? (xa) : (cs * (xa) - sn * (xb));          \
        const float xtB = sn * (xa) + cs * (xb);                              \
        accA[0] += xtA * (r0).x;  accB[0] += xtB * (r0).x;                    \
        accA[1] += xtA * (r0).y;  accB[1] += xtB * (r0).y;                    \
        accA[2] += xtA * (r0).z;  accB[2] += xtB * (r0).z;                    \
        accA[3] += xtA * (r0).w;  accB[3] += xtB * (r0).w;                    \
        accA[4] += xtA * (r1).x;  accB[4] += xtB * (r1).x;                    \
        accA[5] += xtA * (r1).y;  accB[5] += xtB * (r1).y;                    \
        accA[6] += xtA * (r1).z;  accB[6] += xtB * (r1).z;                    \
        accA[7] += xtA * (r1).w;  accB[7] += xtB * (r1).w;                    \
        accA[8] += xtA * (r2).x;  accB[8] += xtB * (r2).x;                    \
        accA[9] += xtA * (r2).y;  accB[9] += xtB * (r2).y;                    \
    } while (0)

    if (deg > 0) {
        // prologue: pair-0 srcs + records (clamped)
        int s0 = RFL(srcs[base]);
        int s1i = (deg > 1) ? RFL(srcs[base + 1]) : s0;
        const float4* rb0 = recs + (size_t)base * 3;
        const float4* rb1 = recs + (size_t)(base + ((deg > 1) ? 1 : 0)) * 3;
        float4 cA0 = rb0[0], cA1 = rb0[1], cA2 = rb0[2];
        float4 cB0 = rb1[0], cB1 = rb1[1], cB2 = rb1[2];

        int i = 0;
        for (; i + 2 <= deg; i += 2) {
            // x gathers: addresses ready NOW
            const float* xr0 = xin + (size_t)s0 * CQ;
            const float* xr1 = xin + (size_t)s1i * CQ;
            const float xa0 = xr0[cqA], xb0 = xr0[cqB];
            const float xa1 = xr1[cqA], xb1 = xr1[cqB];
            // prefetch next window (clamped to last slot)
            const int t0 = (i + 2 < deg) ? i + 2 : deg - 1;
            const int t1 = (i + 3 < deg) ? i + 3 : deg - 1;
            const int ns0 = RFL(srcs[base + t0]);
            const int ns1 = RFL(srcs[base + t1]);
            const float4* np0 = recs + (size_t)(base + t0) * 3;
            const float4* np1 = recs + (size_t)(base + t1) * 3;
            const float4 nA0 = np0[0], nA1 = np0[1], nA2 = np0[2];
            const float4 nB0 = np1[0], nB1 = np1[1], nB2 = np1[2];
            EDGE_FMA(cA0, cA1, cA2, xa0, xb0);
            EDGE_FMA(cB0, cB1, cB2, xa1, xb1);
            s0 = ns0; s1i = ns1;
            cA0 = nA0; cA1 = nA1; cA2 = nA2;
            cB0 = nB0; cB1 = nB1; cB2 = nB2;
        }
        if (i < deg) {   // rem == 1; cA* holds slot i (loaded by last prefetch
                         // or, if deg==1, by the prologue)
            const float* xr = xin + (size_t)s0 * CQ;
            const float xa = xr[cqA], xb = xr[cqB];
            EDGE_FMA(cA0, cA1, cA2, xa, xb);
        }
    }
#undef EDGE_FMA

    // ---- A-row write (k = cq*10 + fr), self column, zero pad ----
    if (lane < 48) {
        unsigned* awA = (unsigned*)&A_s[wid * APAD + cqA * 10];
        awA[0] = pack2h(accA[0], accA[1]);
        awA[1] = pack2h(accA[2], accA[3]);
        awA[2] = pack2h(accA[4], accA[5]);
        awA[3] = pack2h(accA[6], accA[7]);
        awA[4] = pack2h(accA[8], accA[9]);
        A_s[wid * APAD + 800 + cqA] = f2h_u(xin[(size_t)n * CQ + cqA]);
        if (g != 0) {
            unsigned* awB = (unsigned*)&A_s[wid * APAD + cqB * 10];
            awB[0] = pack2h(accB[0], accB[1]);
            awB[1] = pack2h(accB[2], accB[3]);
            awB[2] = pack2h(accB[4], accB[5]);
            awB[3] = pack2h(accB[6], accB[7]);
            awB[4] = pack2h(accB[8], accB[9]);
            A_s[wid * APAD + 800 + cqB] = f2h_u(xin[(size_t)n * CQ + cqB]);
        }
    }
    if (lane < 16) A_s[wid * APAD + 880 + lane] = 0;

    __syncthreads();

    // ---- GEMM: y[16 x 80] = A_s[16 x 896] @ B'[896 x 80] (waves 0-4) ----
    if (tid < 320) {
        const int nt = tid >> 6, lq = tid & 63;
        const int lrow = lq & 15, quad = lq >> 4;
        const f16x8* __restrict__ wf = (const f16x8*)Wt;
        f32x4 acc = (f32x4){0.f, 0.f, 0.f, 0.f};
        #pragma unroll 4
        for (int ks = 0; ks < KS; ++ks) {
            f16x8 bfrag = wf[(ks * 5 + nt) * 64 + lq];
            f16x8 a = *(const f16x8*)(&A_s[lrow * APAD + 32 * ks + 8 * quad]);
            acc = __builtin_amdgcn_mfma_f32_16x16x32_f16(a, bfrag, acc, 0, 0, 0);
        }
        const int op = 16 * nt + lrow;
        const float bias = (op % 5 == 0) ? b[op / 5] : 0.0f;
        #pragma unroll
        for (int r = 0; r < 4; ++r)
            y_s[(quad * 4 + r) * OP + op] = acc[r] + bias;
    }
    __syncthreads();

    // ---- epilogue: 256 threads, one (node, channel) each ----
    if (tid < 256) {
        const int nl = tid >> 4;                 // node 0..15
        const int ch = tid & 15;                 // channel
        const float* vp = &y_s[nl * OP + ch * 5];
        float a0 = vp[0], a1 = vp[1], a2 = vp[2], a3 = vp[3], a4 = vp[4];
        if (res != nullptr) {
            const float* rp = res + (size_t)(n0 + nl) * CQ + ch * 5;
            a0 += rp[0]; a1 += rp[1]; a2 += rp[2]; a3 += rp[3]; a4 += rp[4];
        }
        float o0 = 0.f, o1 = 0.f, o2 = 0.f, o3 = 0.f, o4 = 0.f;
        #pragma unroll
        for (int k = 0; k < 7; ++k) {
            float th = (float)(2.0 * M_PI / 7.0) * (float)k;
            float c1k = cosf(th), s1k = sinf(th);
            float c2k = cosf(2.0f * th), s2k = sinf(2.0f * th);
            float s = a0 + a1 * c1k + a2 * s1k + a3 * c2k + a4 * s2k;
            s = fmaxf(s, 0.0f);
            o0 += s;
            o1 += s * c1k; o2 += s * s1k;
            o3 += s * c2k; o4 += s * s2k;
        }
        const float i7 = 1.0f / 7.0f, t7 = 2.0f / 7.0f;
        float* po = outp + (size_t)(n0 + nl) * OP + ch * 5;
        po[0] = o0 * i7;
        po[1] = o1 * t7; po[2] = o2 * t7;
        po[3] = o3 * t7; po[4] = o4 * t7;
    }
}

// ---------------------------------------------------------------------------
extern "C" void kernel_launch(void* const* d_in, const int* in_sizes, int n_in,
                              void* d_out, int out_size, void* d_ws, size_t ws_size,
                              hipStream_t stream) {
    const float* x    = (const float*)d_in[0];
    const int*   ei   = (const int*)d_in[1];      // int inputs arrive as int32
    const float* pre  = (const float*)d_in[2];
    const float* phi  = (const float*)d_in[3];
    const float* W1   = (const float*)d_in[4];
    const float* b1   = (const float*)d_in[5];
    const float* Ws1  = (const float*)d_in[6];
    const float* W2   = (const float*)d_in[7];
    const float* b2   = (const float*)d_in[8];
    const float* Ws2  = (const float*)d_in[9];
    float* out = (float*)d_out;

    // Workspace layout (~37 MB of the 256 MB ws)
    unsigned short* Wt1 = (unsigned short*)d_ws;            // 143.4 KB
    unsigned short* Wt2 = Wt1 + WTN;                        // 143.4 KB
    float* h  = (float*)(Wt2 + WTN);                        // 3.2 MB
    float4* recs = (float4*)(h + (size_t)NN * OP);          // 30.72 MB (16B aligned)
    int* srcs   = (int*)(recs + (size_t)NN * MAXDEG * 3);   // 2.56 MB
    int* cnt    = srcs + (size_t)NN * MAXDEG;               // 40 KB

    // 4-dispatch chain: memset -> prep_all -> layer1 -> layer2
    hipMemsetAsync(cnt, 0, NN * sizeof(int), stream);
    prep_all<<<(NE + 255) / 256, 256, 0, stream>>>(ei, phi, pre, W1, Ws1, W2, Ws2,
                                                   cnt, srcs, recs, Wt1, Wt2);
    layer_fused<<<NN / 16, 1024, 0, stream>>>(x, srcs, recs, cnt, Wt1, b1, nullptr, h);
    layer_fused<<<NN / 16, 1024, 0, stream>>>(h, srcs, recs, cnt, Wt2, b2, x, out);
}

// Round 10
// 149.161 us; speedup vs baseline: 1.6638x; 1.0082x over previous
//
#include <hip/hip_runtime.h>
#include <hip/hip_bf16.h>
#include <hip/hip_fp16.h>
#include <math.h>

#ifndef M_PI
#define M_PI 3.14159265358979323846
#endif

// Problem constants
#define NN 10000      // nodes
#define NE 160000     // edges
#define NC 16         // channels
#define NQ 5          // 2*order+1
#define NFR 10        // N_FREQ * N_RINGS
#define CQ 80         // NC*NQ
#define OP 80         // outputs per node

// Fixed-bucket edge store: node n owns slots [n*MAXDEG, n*MAXDEG+deg).
// deg ~ Binomial(160000,1e-4): mean 16, sd 4; 64 = 12 sd -> safe for any seed.
#define MAXDEG 64

// Extended GEMM: k in [0,800) edge-aggregate part with k = cq*10 + fr;
//                k in [800,880) self-interaction part with k = 800 + cq;
//                k in [880,896) zero pad (both A and B written as 0).
#define KTOT2 896
#define KS 28         // 896 / 32 MFMA k-steps
#define WTN 71680     // KTOT2 * 80 weight elements per layer
#define APAD 936      // LDS row stride fp16: 468 dwords = 20 mod 32 banks (v12-proven residue)

// v20 block geometry: 8 nodes / 8 waves / 512 threads, 4 blocks/CU co-resident
#define NPB 8         // nodes per block

typedef __attribute__((ext_vector_type(8))) _Float16 f16x8;
typedef __attribute__((ext_vector_type(4))) float f32x4;

static __device__ __forceinline__ unsigned short f2h_u(float f) {
    return __builtin_bit_cast(unsigned short, (_Float16)f);
}
static __device__ __forceinline__ unsigned pack2h(float lo, float hi) {
    return (unsigned)f2h_u(lo) | ((unsigned)f2h_u(hi) << 16);
}
#define RFL(x) __builtin_amdgcn_readfirstlane(x)

// ---------------------------------------------------------------------------
// prep_all: ONE dispatch does everything the layers need.
//  i < NE:  edge i claims rank = atomicAdd(cnt[dst]) and writes its record
//           {tv[0..9], c1, s1} (48 B) + src id into node dst's fixed bucket.
//  i < WTN: reorder W+Ws into MFMA-B fragment order (k-map above, R10-proven).
// ---------------------------------------------------------------------------
__global__ void prep_all(const int* __restrict__ ei, const float* __restrict__ phi,
                         const float* __restrict__ pre,
                         const float* __restrict__ W1, const float* __restrict__ Ws1,
                         const float* __restrict__ W2, const float* __restrict__ Ws2,
                         int* __restrict__ cnt, int* __restrict__ srcs,
                         float4* __restrict__ recs,
                         unsigned short* __restrict__ Wt1, unsigned short* __restrict__ Wt2) {
    int i = blockIdx.x * blockDim.x + threadIdx.x;
    if (i < NE) {
        const int dst  = ei[2 * i + 1];
        const int srcn = ei[2 * i];
        const int rank = atomicAdd(&cnt[dst], 1);
        if (rank < MAXDEG) {               // can't overflow for this dataset; guard vs OOB
            float s1, c1;
            sincosf(phi[i], &s1, &c1);
            const float* tp = pre + (size_t)i * NFR;
            const int slot = dst * MAXDEG + rank;
            float4* rp = recs + (size_t)slot * 3;
            rp[0] = make_float4(tp[0], tp[1], tp[2], tp[3]);
            rp[1] = make_float4(tp[4], tp[5], tp[6], tp[7]);
            rp[2] = make_float4(tp[8], tp[9], c1, s1);
            srcs[slot] = srcn;
        }
    }
    if (i < WTN) {
        int j    = i & 7;
        int lane = (i >> 3) & 63;
        int grp  = i >> 9;            // 0..139 = ks*5 + nt
        int ks   = grp / 5;
        int nt   = grp % 5;
        int quad = lane >> 4;
        int lrow = lane & 15;
        int n    = 16 * nt + lrow;    // output index op
        int k    = 32 * ks + 8 * quad + j;
        int o = n / 5, p = n % 5;
        float v1, v2;
        if (k < 800) {                // edge part: k = cq*10 + fr
            int cq = k / 10, fr = k % 10;
            int c = cq / 5, q = cq % 5;
            int f = fr >> 1, r = fr & 1;
            int src = ((((o * NC + c) * NQ + p) * NQ + q) * 5 + f) * 2 + r;
            v1 = W1[src]; v2 = W2[src];
        } else if (k < 880) {         // self part: k = 800 + cq
            int cq = k - 800;
            int c = cq / 5, q = cq % 5;
            int src = ((o * NC + c) * NQ + p) * NQ + q;
            v1 = Ws1[src]; v2 = Ws2[src];
        } else {                      // pad
            v1 = 0.0f; v2 = 0.0f;
        }
        Wt1[i] = f2h_u(v1); Wt2[i] = f2h_u(v2);
    }
}

// ---------------------------------------------------------------------------
// layer_fused v20: ONE WAVE PER NODE, 8 nodes / 512 threads per block.
//
// R9 post-mortem: at 16-wave blocks the 32-waves/CU cap allows only 2 blocks
// co-resident; each block's barrier'd GEMM (5/16 waves) and epilogue (4/16)
// phases left the CU near-idle -> layers ~30-38 us despite a ~6-10 us issue
// model. v20 halves the block: 4 blocks/CU co-resident, phases overlap
// ACROSS blocks, VGPR cap relaxes 128->256.
//
// GEMM on an 8-row A tile: MFMA reads A row (lrow&7); D rows 8-15 are
// duplicates of 0-7 (D row i depends only on A row i) and are discarded
// (store gated to quad<2) -> node outputs bit-identical to v18.
// Aggregation loop, lane map, and epilogue math unchanged from passing v18.
// ---------------------------------------------------------------------------
__global__ __launch_bounds__(512)
void layer_fused(const float* __restrict__ xin, const int* __restrict__ srcs,
                 const float4* __restrict__ recs, const int* __restrict__ cnt,
                 const unsigned short* __restrict__ Wt, const float* __restrict__ b,
                 const float* __restrict__ res,   // residual (x) or nullptr
                 float* __restrict__ outp) {
    __shared__ __align__(16) unsigned short A_s[NPB * APAD];  // 14,976 B
    __shared__ float y_s[NPB * OP];                           //  2,560 B

    const int tid = threadIdx.x;
    const int n0 = blockIdx.x * NPB;             // NN = 1250*8 exactly
    const int wid = RFL(tid >> 6);               // wave id = local node (SGPR)
    const int lane = tid & 63;
    const int n = n0 + wid;

    // ---- lane roles (clamped for lanes 48..63 -> in-bounds dummy work) ----
    const int l48 = (lane < 48) ? lane : 0;
    const int c   = l48 / 3;
    const int g   = l48 - 3 * c;                 // 0,1,2
    const int cqA = 5 * c + ((g == 0) ? 0 : (g == 1) ? 1 : 3);
    const int cqB = cqA + 1;                     // partner (ignored for g==0)
    const bool hi = (g == 2);

    const int base = n * MAXDEG;
    int deg = RFL(cnt[n]);
    if (deg > MAXDEG) deg = MAXDEG;

    float accA[10], accB[10];
    #pragma unroll
    for (int f = 0; f < 10; ++f) { accA[f] = 0.f; accB[f] = 0.f; }

    // EDGE: record floats are SGPR (uniform); xa/xb per-lane VGPR loads.
#define EDGE_FMA(r0, r1, r2, xa, xb)                                          \
    do {                                                                      \
        const float c1 = (r2).z, s1 = (r2).w;                                 \
        const float c2 = c1 * c1 - s1 * s1;                                   \
        const float s2 = 2.0f * c1 * s1;                                      \
        const float cs = hi ? c2 : c1;                                        \
        const float sn = hi ? s2 : s1;                                        \
        const float xtA = (g == 0) ? (xa) : (cs * (xa) - sn * (xb));          \
        const float xtB = sn * (xa) + cs * (xb);                              \
        accA[0] += xtA * (r0).x;  accB[0] += xtB * (r0).x;                    \
        accA[1] += xtA * (r0).y;  accB[1] += xtB * (r0).y;                    \
        accA[2] += xtA * (r0).z;  accB[2] += xtB * (r0).z;                    \
        accA[3] += xtA * (r0).w;  accB[3] += xtB * (r0).w;                    \
        accA[4] += xtA * (r1).x;  accB[4] += xtB * (r1).x;                    \
        accA[5] += xtA * (r1).y;  accB[5] += xtB * (r1).y;                    \
        accA[6] += xtA * (r1).z;  accB[6] += xtB * (r1).z;                    \
        accA[7] += xtA * (r1).w;  accB[7] += xtB * (r1).w;                    \
        accA[8] += xtA * (r2).x;  accB[8] += xtB * (r2).x;                    \
        accA[9] += xtA * (r2).y;  accB[9] += xtB * (r2).y;                    \
    } while (0)

    if (deg > 0) {
        // prologue: pair-0 srcs + records (clamped)
        int s0 = RFL(srcs[base]);
        int s1i = (deg > 1) ? RFL(srcs[base + 1]) : s0;
        const float4* rb0 = recs + (size_t)base * 3;
        const float4* rb1 = recs + (size_t)(base + ((deg > 1) ? 1 : 0)) * 3;
        float4 cA0 = rb0[0], cA1 = rb0[1], cA2 = rb0[2];
        float4 cB0 = rb1[0], cB1 = rb1[1], cB2 = rb1[2];

        int i = 0;
        for (; i + 2 <= deg; i += 2) {
            // x gathers: addresses ready NOW
            const float* xr0 = xin + (size_t)s0 * CQ;
            const float* xr1 = xin + (size_t)s1i * CQ;
            const float xa0 = xr0[cqA], xb0 = xr0[cqB];
            const float xa1 = xr1[cqA], xb1 = xr1[cqB];
            // prefetch next window (clamped to last slot)
            const int t0 = (i + 2 < deg) ? i + 2 : deg - 1;
            const int t1 = (i + 3 < deg) ? i + 3 : deg - 1;
            const int ns0 = RFL(srcs[base + t0]);
            const int ns1 = RFL(srcs[base + t1]);
            const float4* np0 = recs + (size_t)(base + t0) * 3;
            const float4* np1 = recs + (size_t)(base + t1) * 3;
            const float4 nA0 = np0[0], nA1 = np0[1], nA2 = np0[2];
            const float4 nB0 = np1[0], nB1 = np1[1], nB2 = np1[2];
            EDGE_FMA(cA0, cA1, cA2, xa0, xb0);
            EDGE_FMA(cB0, cB1, cB2, xa1, xb1);
            s0 = ns0; s1i = ns1;
            cA0 = nA0; cA1 = nA1; cA2 = nA2;
            cB0 = nB0; cB1 = nB1; cB2 = nB2;
        }
        if (i < deg) {   // rem == 1; cA* holds slot i (loaded by last prefetch
                         // or, if deg==1, by the prologue)
            const float* xr = xin + (size_t)s0 * CQ;
            const float xa = xr[cqA], xb = xr[cqB];
            EDGE_FMA(cA0, cA1, cA2, xa, xb);
        }
    }
#undef EDGE_FMA

    // ---- A-row write (k = cq*10 + fr), self column, zero pad ----
    if (lane < 48) {
        unsigned* awA = (unsigned*)&A_s[wid * APAD + cqA * 10];
        awA[0] = pack2h(accA[0], accA[1]);
        awA[1] = pack2h(accA[2], accA[3]);
        awA[2] = pack2h(accA[4], accA[5]);
        awA[3] = pack2h(accA[6], accA[7]);
        awA[4] = pack2h(accA[8], accA[9]);
        A_s[wid * APAD + 800 + cqA] = f2h_u(xin[(size_t)n * CQ + cqA]);
        if (g != 0) {
            unsigned* awB = (unsigned*)&A_s[wid * APAD + cqB * 10];
            awB[0] = pack2h(accB[0], accB[1]);
            awB[1] = pack2h(accB[2], accB[3]);
            awB[2] = pack2h(accB[4], accB[5]);
            awB[3] = pack2h(accB[6], accB[7]);
            awB[4] = pack2h(accB[8], accB[9]);
            A_s[wid * APAD + 800 + cqB] = f2h_u(xin[(size_t)n * CQ + cqB]);
        }
    }
    if (lane < 16) A_s[wid * APAD + 880 + lane] = 0;

    __syncthreads();

    // ---- GEMM: y[8 x 80] = A_s[8 x 896] @ B'[896 x 80] (waves 0-4) ----
    // A row = lrow&7 (rows 8-15 duplicate rows 0-7; D rows 8-15 discarded).
    if (tid < 320) {
        const int nt = tid >> 6, lq = tid & 63;
        const int lrow = lq & 15, quad = lq >> 4;
        const int arow = lrow & 7;
        const f16x8* __restrict__ wf = (const f16x8*)Wt;
        f32x4 acc = (f32x4){0.f, 0.f, 0.f, 0.f};
        #pragma unroll 4
        for (int ks = 0; ks < KS; ++ks) {
            f16x8 bfrag = wf[(ks * 5 + nt) * 64 + lq];
            f16x8 a = *(const f16x8*)(&A_s[arow * APAD + 32 * ks + 8 * quad]);
            acc = __builtin_amdgcn_mfma_f32_16x16x32_f16(a, bfrag, acc, 0, 0, 0);
        }
        const int op = 16 * nt + lrow;
        const float bias = (op % 5 == 0) ? b[op / 5] : 0.0f;
        if (quad < 2) {                          // D rows 0..7 only
            #pragma unroll
            for (int r = 0; r < 4; ++r)
                y_s[(quad * 4 + r) * OP + op] = acc[r] + bias;
        }
    }
    __syncthreads();

    // ---- epilogue: 128 threads, one (node, channel) each ----
    if (tid < 128) {
        const int nl = tid >> 4;                 // node 0..7
        const int ch = tid & 15;                 // channel
        const float* vp = &y_s[nl * OP + ch * 5];
        float a0 = vp[0], a1 = vp[1], a2 = vp[2], a3 = vp[3], a4 = vp[4];
        if (res != nullptr) {
            const float* rp = res + (size_t)(n0 + nl) * CQ + ch * 5;
            a0 += rp[0]; a1 += rp[1]; a2 += rp[2]; a3 += rp[3]; a4 += rp[4];
        }
        float o0 = 0.f, o1 = 0.f, o2 = 0.f, o3 = 0.f, o4 = 0.f;
        #pragma unroll
        for (int k = 0; k < 7; ++k) {
            float th = (float)(2.0 * M_PI / 7.0) * (float)k;
            float c1k = cosf(th), s1k = sinf(th);
            float c2k = cosf(2.0f * th), s2k = sinf(2.0f * th);
            float s = a0 + a1 * c1k + a2 * s1k + a3 * c2k + a4 * s2k;
            s = fmaxf(s, 0.0f);
            o0 += s;
            o1 += s * c1k; o2 += s * s1k;
            o3 += s * c2k; o4 += s * s2k;
        }
        const float i7 = 1.0f / 7.0f, t7 = 2.0f / 7.0f;
        float* po = outp + (size_t)(n0 + nl) * OP + ch * 5;
        po[0] = o0 * i7;
        po[1] = o1 * t7; po[2] = o2 * t7;
        po[3] = o3 * t7; po[4] = o4 * t7;
    }
}

// ---------------------------------------------------------------------------
extern "C" void kernel_launch(void* const* d_in, const int* in_sizes, int n_in,
                              void* d_out, int out_size, void* d_ws, size_t ws_size,
                              hipStream_t stream) {
    const float* x    = (const float*)d_in[0];
    const int*   ei   = (const int*)d_in[1];      // int inputs arrive as int32
    const float* pre  = (const float*)d_in[2];
    const float* phi  = (const float*)d_in[3];
    const float* W1   = (const float*)d_in[4];
    const float* b1   = (const float*)d_in[5];
    const float* Ws1  = (const float*)d_in[6];
    const float* W2   = (const float*)d_in[7];
    const float* b2   = (const float*)d_in[8];
    const float* Ws2  = (const float*)d_in[9];
    float* out = (float*)d_out;

    // Workspace layout (~37 MB of the 256 MB ws)
    unsigned short* Wt1 = (unsigned short*)d_ws;            // 143.4 KB
    unsigned short* Wt2 = Wt1 + WTN;                        // 143.4 KB
    float* h  = (float*)(Wt2 + WTN);                        // 3.2 MB
    float4* recs = (float4*)(h + (size_t)NN * OP);          // 30.72 MB (16B aligned)
    int* srcs   = (int*)(recs + (size_t)NN * MAXDEG * 3);   // 2.56 MB
    int* cnt    = srcs + (size_t)NN * MAXDEG;               // 40 KB

    // 4-dispatch chain: memset -> prep_all -> layer1 -> layer2
    hipMemsetAsync(cnt, 0, NN * sizeof(int), stream);
    prep_all<<<(NE + 255) / 256, 256, 0, stream>>>(ei, phi, pre, W1, Ws1, W2, Ws2,
                                                   cnt, srcs, recs, Wt1, Wt2);
    layer_fused<<<NN / NPB, 512, 0, stream>>>(x, srcs, recs, cnt, Wt1, b1, nullptr, h);
    layer_fused<<<NN / NPB, 512, 0, stream>>>(h, srcs, recs, cnt, Wt2, b2, x, out);
}

// Round 12
// 145.239 us; speedup vs baseline: 1.7087x; 1.0270x over previous
//
#include <hip/hip_runtime.h>
#include <hip/hip_bf16.h>
#include <hip/hip_fp16.h>
#include <math.h>

#ifndef M_PI
#define M_PI 3.14159265358979323846
#endif

// Problem constants
#define NN 10000      // nodes
#define NE 160000     // edges
#define NC 16         // channels
#define NQ 5          // 2*order+1
#define NFR 10        // N_FREQ * N_RINGS
#define CQ 80         // NC*NQ
#define OP 80         // outputs per node

// Fixed-bucket edge store: node n owns slots [n*MAXDEG, n*MAXDEG+deg).
// deg ~ Binomial(160000,1e-4): mean 16, sd 4; 64 = 12 sd -> safe for any seed.
#define MAXDEG 64

// Extended GEMM: k in [0,800) edge part (k = cq*10 + fr); k in [800,880)
// self part (k = 800 + cq); k in [880,896) zero pad (A and B both zero).
#define KTOT2 896
#define KS 28         // 896 / 32 MFMA k-steps
#define WTN 71680     // KTOT2 * 80 weight elements per layer
#define APAD 936      // LDS row stride fp16 (20 mod 32 banks, v12-proven)
#define NPB 8         // nodes per block (8 waves, 512 threads)

typedef __attribute__((ext_vector_type(8))) _Float16 f16x8;
typedef __attribute__((ext_vector_type(4))) float f32x4;

static __device__ __forceinline__ unsigned short f2h_u(float f) {
    return __builtin_bit_cast(unsigned short, (_Float16)f);
}
static __device__ __forceinline__ unsigned pack2h(float lo, float hi) {
    return (unsigned)f2h_u(lo) | ((unsigned)f2h_u(hi) << 16);
}
#define RFL(x) __builtin_amdgcn_readfirstlane(x)

// ---------------------------------------------------------------------------
// prep_all: ONE dispatch does everything the layers need.
//  i < NE:  edge i claims rank = atomicAdd(cnt[dst]) and writes its record
//           {tv[0..9], c1, s1} (48 B) + src id into node dst's fixed bucket.
//  i < WTN: reorder W+Ws into MFMA-B fragment order (k-map above, R10-proven).
// ---------------------------------------------------------------------------
__global__ void prep_all(const int* __restrict__ ei, const float* __restrict__ phi,
                         const float* __restrict__ pre,
                         const float* __restrict__ W1, const float* __restrict__ Ws1,
                         const float* __restrict__ W2, const float* __restrict__ Ws2,
                         int* __restrict__ cnt, int* __restrict__ srcs,
                         float4* __restrict__ recs,
                         unsigned short* __restrict__ Wt1, unsigned short* __restrict__ Wt2) {
    int i = blockIdx.x * blockDim.x + threadIdx.x;
    if (i < NE) {
        const int dst  = ei[2 * i + 1];
        const int srcn = ei[2 * i];
        const int rank = atomicAdd(&cnt[dst], 1);
        if (rank < MAXDEG) {               // can't overflow for this dataset; guard vs OOB
            float s1, c1;
            sincosf(phi[i], &s1, &c1);
            const float* tp = pre + (size_t)i * NFR;
            const int slot = dst * MAXDEG + rank;
            float4* rp = recs + (size_t)slot * 3;
            rp[0] = make_float4(tp[0], tp[1], tp[2], tp[3]);
            rp[1] = make_float4(tp[4], tp[5], tp[6], tp[7]);
            rp[2] = make_float4(tp[8], tp[9], c1, s1);
            srcs[slot] = srcn;
        }
    }
    if (i < WTN) {
        int j    = i & 7;
        int lane = (i >> 3) & 63;
        int grp  = i >> 9;            // 0..139 = ks*5 + nt
        int ks   = grp / 5;
        int nt   = grp % 5;
        int quad = lane >> 4;
        int lrow = lane & 15;
        int n    = 16 * nt + lrow;    // output index op
        int k    = 32 * ks + 8 * quad + j;
        int o = n / 5, p = n % 5;
        float v1, v2;
        if (k < 800) {                // edge part: k = cq*10 + fr
            int cq = k / 10, fr = k % 10;
            int c = cq / 5, q = cq % 5;
            int f = fr >> 1, r = fr & 1;
            int src = ((((o * NC + c) * NQ + p) * NQ + q) * 5 + f) * 2 + r;
            v1 = W1[src]; v2 = W2[src];
        } else if (k < 880) {         // self part: k = 800 + cq
            int cq = k - 800;
            int c = cq / 5, q = cq % 5;
            int src = ((o * NC + c) * NQ + p) * NQ + q;
            v1 = Ws1[src]; v2 = Ws2[src];
        } else {                      // pad
            v1 = 0.0f; v2 = 0.0f;
        }
        Wt1[i] = f2h_u(v1); Wt2[i] = f2h_u(v2);
    }
}

// ---------------------------------------------------------------------------
// layer_fused v22 = verified v20 (8 nodes / 512 threads, 1 wave/node,
// wave-uniform SGPR records, 4 blocks/CU) + DEPTH-2 edge pipeline:
// x-values for window w+1 load during window w's FMAs (addresses available
// from srcs prefetched 2 windows back); srcs/recs prefetch 2 windows deep.
// FMAs execute in slot order -> accumulation bit-identical to v20.
// R11's cooperative single-kernel variant is abandoned (silent launch-failure
// risk); this isolates the one sound lever on the passing structure.
// ---------------------------------------------------------------------------
__global__ __launch_bounds__(512)
void layer_fused(const float* __restrict__ xin, const int* __restrict__ srcs,
                 const float4* __restrict__ recs, const int* __restrict__ cnt,
                 const unsigned short* __restrict__ Wt, const float* __restrict__ b,
                 const float* __restrict__ res,   // residual (x) or nullptr
                 float* __restrict__ outp) {
    __shared__ __align__(16) unsigned short A_s[NPB * APAD];  // 14,976 B
    __shared__ float y_s[NPB * OP];                           //  2,560 B

    const int tid = threadIdx.x;
    const int n0 = blockIdx.x * NPB;             // NN = 1250*8 exactly
    const int wid = RFL(tid >> 6);               // wave id = local node (SGPR)
    const int lane = tid & 63;
    const int n = n0 + wid;

    // ---- lane roles (lanes 48..63 clamped to in-bounds dummy work) ----
    const int l48 = (lane < 48) ? lane : 0;
    const int c   = l48 / 3;
    const int g   = l48 - 3 * c;                 // 0,1,2
    const int cqA = 5 * c + ((g == 0) ? 0 : (g == 1) ? 1 : 3);
    const int cqB = cqA + 1;                     // partner (ignored for g==0)
    const bool hi = (g == 2);

    const int base = n * MAXDEG;
    int deg = RFL(cnt[n]);
    if (deg > MAXDEG) deg = MAXDEG;

    float accA[10], accB[10];
    #pragma unroll
    for (int f = 0; f < 10; ++f) { accA[f] = 0.f; accB[f] = 0.f; }

    // EDGE: record floats are SGPR (uniform); xa/xb per-lane VGPR loads.
#define EDGE_FMA(r0, r1, r2, xa, xb)                                          \
    do {                                                                      \
        const float c1 = (r2).z, s1 = (r2).w;                                 \
        const float c2 = c1 * c1 - s1 * s1;                                   \
        const float s2 = 2.0f * c1 * s1;                                      \
        const float cs = hi ? c2 : c1;                                        \
        const float sn = hi ? s2 : s1;                                        \
        const float xtA = (g == 0) ? (xa) : (cs * (xa) - sn * (xb));          \
        const float xtB = sn * (xa) + cs * (xb);                              \
        accA[0] += xtA * (r0).x;  accB[0] += xtB * (r0).x;                    \
        accA[1] += xtA * (r0).y;  accB[1] += xtB * (r0).y;                    \
        accA[2] += xtA * (r0).z;  accB[2] += xtB * (r0).z;                    \
        accA[3] += xtA * (r0).w;  accB[3] += xtB * (r0).w;                    \
        accA[4] += xtA * (r1).x;  accB[4] += xtB * (r1).x;                    \
        accA[5] += xtA * (r1).y;  accB[5] += xtB * (r1).y;                    \
        accA[6] += xtA * (r1).z;  accB[6] += xtB * (r1).z;                    \
        accA[7] += xtA * (r1).w;  accB[7] += xtB * (r1).w;                    \
        accA[8] += xtA * (r2).x;  accB[8] += xtB * (r2).x;                    \
        accA[9] += xtA * (r2).y;  accB[9] += xtB * (r2).y;                    \
    } while (0)

    if (deg > 0) {
        // slot(i): clamped bucket index (prefetch-safe, always in-bounds)
        #define SLOT(i) (base + (((i) < deg) ? (i) : (deg - 1)))
        // ---- depth-2 prologue: windows 0 (slots 0,1) and 1 (slots 2,3) ----
        int sA0 = RFL(srcs[SLOT(0)]);
        int sB0 = RFL(srcs[SLOT(1)]);
        int sA1 = RFL(srcs[SLOT(2)]);
        int sB1 = RFL(srcs[SLOT(3)]);
        const float4* p;
        p = recs + (size_t)SLOT(0) * 3; float4 rA0a = p[0], rA0b = p[1], rA0c = p[2];
        p = recs + (size_t)SLOT(1) * 3; float4 rB0a = p[0], rB0b = p[1], rB0c = p[2];
        p = recs + (size_t)SLOT(2) * 3; float4 rA1a = p[0], rA1b = p[1], rA1c = p[2];
        p = recs + (size_t)SLOT(3) * 3; float4 rB1a = p[0], rB1b = p[1], rB1c = p[2];
        const float* xr;
        xr = xin + (size_t)sA0 * CQ; float xaA = xr[cqA], xbA = xr[cqB];
        xr = xin + (size_t)sB0 * CQ; float xaB = xr[cqA], xbB = xr[cqB];

        int i = 0;
        for (; i + 2 <= deg; i += 2) {
            // prefetch srcs window w+2
            const int nsA = RFL(srcs[SLOT(i + 4)]);
            const int nsB = RFL(srcs[SLOT(i + 5)]);
            // prefetch x window w+1 (addresses ready: sA1/sB1)
            const float* x1 = xin + (size_t)sA1 * CQ;
            const float* x2 = xin + (size_t)sB1 * CQ;
            const float nxaA = x1[cqA], nxbA = x1[cqB];
            const float nxaB = x2[cqA], nxbB = x2[cqB];
            // prefetch recs window w+2
            const float4* q1 = recs + (size_t)SLOT(i + 4) * 3;
            const float4* q2 = recs + (size_t)SLOT(i + 5) * 3;
            const float4 nrAa = q1[0], nrAb = q1[1], nrAc = q1[2];
            const float4 nrBa = q2[0], nrBb = q2[1], nrBc = q2[2];
            // compute window w (slot order preserved -> v20-identical values)
            EDGE_FMA(rA0a, rA0b, rA0c, xaA, xbA);
            EDGE_FMA(rB0a, rB0b, rB0c, xaB, xbB);
            // rotate pipeline state
            sA0 = sA1; sB0 = sB1; sA1 = nsA; sB1 = nsB;
            xaA = nxaA; xbA = nxbA; xaB = nxaB; xbB = nxbB;
            rA0a = rA1a; rA0b = rA1b; rA0c = rA1c;
            rB0a = rB1a; rB0b = rB1b; rB0c = rB1c;
            rA1a = nrAa; rA1b = nrAb; rA1c = nrAc;
            rB1a = nrBa; rB1b = nrBb; rB1c = nrBc;
        }
        if (deg & 1) {   // tail edge deg-1: A0/x state holds slot(deg-1)
            EDGE_FMA(rA0a, rA0b, rA0c, xaA, xbA);
        }
        #undef SLOT
    }
#undef EDGE_FMA

    // ---- A-row write (k = cq*10 + fr), self column, zero pad ----
    if (lane < 48) {
        unsigned* awA = (unsigned*)&A_s[wid * APAD + cqA * 10];
        awA[0] = pack2h(accA[0], accA[1]);
        awA[1] = pack2h(accA[2], accA[3]);
        awA[2] = pack2h(accA[4], accA[5]);
        awA[3] = pack2h(accA[6], accA[7]);
        awA[4] = pack2h(accA[8], accA[9]);
        A_s[wid * APAD + 800 + cqA] = f2h_u(xin[(size_t)n * CQ + cqA]);
        if (g != 0) {
            unsigned* awB = (unsigned*)&A_s[wid * APAD + cqB * 10];
            awB[0] = pack2h(accB[0], accB[1]);
            awB[1] = pack2h(accB[2], accB[3]);
            awB[2] = pack2h(accB[4], accB[5]);
            awB[3] = pack2h(accB[6], accB[7]);
            awB[4] = pack2h(accB[8], accB[9]);
            A_s[wid * APAD + 800 + cqB] = f2h_u(xin[(size_t)n * CQ + cqB]);
        }
    }
    if (lane < 16) A_s[wid * APAD + 880 + lane] = 0;

    __syncthreads();

    // ---- GEMM: y[8 x 80] = A_s[8 x 896] @ B'[896 x 80] (waves 0-4) ----
    // A row = lrow&7 (rows 8-15 duplicate rows 0-7; D rows 8-15 discarded).
    if (tid < 320) {
        const int nt = tid >> 6, lq = tid & 63;
        const int lrow = lq & 15, quad = lq >> 4;
        const int arow = lrow & 7;
        const f16x8* __restrict__ wf = (const f16x8*)Wt;
        f32x4 acc = (f32x4){0.f, 0.f, 0.f, 0.f};
        #pragma unroll 4
        for (int ks = 0; ks < KS; ++ks) {
            f16x8 bfrag = wf[(ks * 5 + nt) * 64 + lq];
            f16x8 a = *(const f16x8*)(&A_s[arow * APAD + 32 * ks + 8 * quad]);
            acc = __builtin_amdgcn_mfma_f32_16x16x32_f16(a, bfrag, acc, 0, 0, 0);
        }
        const int op = 16 * nt + lrow;
        const float bias = (op % 5 == 0) ? b[op / 5] : 0.0f;
        if (quad < 2) {                          // D rows 0..7 only
            #pragma unroll
            for (int r = 0; r < 4; ++r)
                y_s[(quad * 4 + r) * OP + op] = acc[r] + bias;
        }
    }
    __syncthreads();

    // ---- epilogue: 128 threads, one (node, channel) each ----
    if (tid < 128) {
        const int nl = tid >> 4;                 // node 0..7
        const int ch = tid & 15;                 // channel
        const float* vp = &y_s[nl * OP + ch * 5];
        float a0 = vp[0], a1 = vp[1], a2 = vp[2], a3 = vp[3], a4 = vp[4];
        if (res != nullptr) {
            const float* rp = res + (size_t)(n0 + nl) * CQ + ch * 5;
            a0 += rp[0]; a1 += rp[1]; a2 += rp[2]; a3 += rp[3]; a4 += rp[4];
        }
        float o0 = 0.f, o1 = 0.f, o2 = 0.f, o3 = 0.f, o4 = 0.f;
        #pragma unroll
        for (int k = 0; k < 7; ++k) {
            float th = (float)(2.0 * M_PI / 7.0) * (float)k;
            float c1k = cosf(th), s1k = sinf(th);
            float c2k = cosf(2.0f * th), s2k = sinf(2.0f * th);
            float s = a0 + a1 * c1k + a2 * s1k + a3 * c2k + a4 * s2k;
            s = fmaxf(s, 0.0f);
            o0 += s;
            o1 += s * c1k; o2 += s * s1k;
            o3 += s * c2k; o4 += s * s2k;
        }
        const float i7 = 1.0f / 7.0f, t7 = 2.0f / 7.0f;
        float* po = outp + (size_t)(n0 + nl) * OP + ch * 5;
        po[0] = o0 * i7;
        po[1] = o1 * t7; po[2] = o2 * t7;
        po[3] = o3 * t7; po[4] = o4 * t7;
    }
}

// ---------------------------------------------------------------------------
extern "C" void kernel_launch(void* const* d_in, const int* in_sizes, int n_in,
                              void* d_out, int out_size, void* d_ws, size_t ws_size,
                              hipStream_t stream) {
    const float* x    = (const float*)d_in[0];
    const int*   ei   = (const int*)d_in[1];      // int inputs arrive as int32
    const float* pre  = (const float*)d_in[2];
    const float* phi  = (const float*)d_in[3];
    const float* W1   = (const float*)d_in[4];
    const float* b1   = (const float*)d_in[5];
    const float* Ws1  = (const float*)d_in[6];
    const float* W2   = (const float*)d_in[7];
    const float* b2   = (const float*)d_in[8];
    const float* Ws2  = (const float*)d_in[9];
    float* out = (float*)d_out;

    // Workspace layout (~37 MB of the 256 MB ws)
    unsigned short* Wt1 = (unsigned short*)d_ws;            // 143.4 KB
    unsigned short* Wt2 = Wt1 + WTN;                        // 143.4 KB
    float* h  = (float*)(Wt2 + WTN);                        // 3.2 MB
    float4* recs = (float4*)(h + (size_t)NN * OP);          // 30.72 MB (16B aligned)
    int* srcs   = (int*)(recs + (size_t)NN * MAXDEG * 3);   // 2.56 MB
    int* cnt    = srcs + (size_t)NN * MAXDEG;               // 40 KB

    // 4-dispatch chain: memset -> prep_all -> layer1 -> layer2
    hipMemsetAsync(cnt, 0, NN * sizeof(int), stream);
    prep_all<<<(NE + 255) / 256, 256, 0, stream>>>(ei, phi, pre, W1, Ws1, W2, Ws2,
                                                   cnt, srcs, recs, Wt1, Wt2);
    layer_fused<<<NN / NPB, 512, 0, stream>>>(x, srcs, recs, cnt, Wt1, b1, nullptr, h);
    layer_fused<<<NN / NPB, 512, 0, stream>>>(h, srcs, recs, cnt, Wt2, b2, x, out);
}